// Round 9
// baseline (188.218 us; speedup 1.0000x reference)
//
#include <hip/hip_runtime.h>

// out[i,v] = sum_j exp(-g*max(xn_i + yn_j - 2 x_i.y_j, 0)) * b[j,v]
// N=M=16384, D=32, Dv=16, fp32.
//
// Round 17: ISOLATE the dep-depth change. r16 bundled {c/d split, dual acc}
// with a prologue relayout (64x256 -> 256x64); FETCH exploded 21->263 MB
// (main-kernel L2 hits on rec0 collapsed -- record->XCD-L2 placement
// changed) and masked the experiment. Revert prologue to r15's exact
// 64-block x 256-thread version; keep ONLY:
//   (a) c/d split: two parallel depth-2 MFMA chains + one add (r8 numerics)
//   (b) dual PV accumulators acc0/acc1 (depth 2 -> 1), summed in epilogue
// vs r15's depth-3 e-chain + depth-2 PV.
// Record per 64-j tile: [yn' 256B | yh 64x80B | yl 64x80B | bTh 16x144B] = 12800 B.

#define NPTS 16384
#define D    32
#define DV   16
#define IBLK 256
#define JSPLIT 16
#define JBLK 64
#define NTILE  (NPTS / JBLK)        // 256
#define TILES  (NTILE / JSPLIT)     // 16 per block
#define REC    12800
#define YH_OFF 256
#define YL_OFF 5376
#define BT_OFF 10496
#define PTS    72                   // bT row stride in halves
#define PART_F4 (NPTS * DV / 4)     // 65536 float4s per slab

typedef _Float16 half8   __attribute__((ext_vector_type(8)));
typedef __fp16   cvt2_t  __attribute__((ext_vector_type(2)));
typedef float    float4_t __attribute__((ext_vector_type(4)));
typedef unsigned int u32;
typedef unsigned int u32x2 __attribute__((ext_vector_type(2)));

__device__ __forceinline__ void async16(const void* g, void* l) {
  __builtin_amdgcn_global_load_lds((const __attribute__((address_space(1))) u32*)g,
                                   (__attribute__((address_space(3))) u32*)l, 16, 0, 0);
}

__device__ __forceinline__ void stage_tile(const char* __restrict__ g,
                                           char* __restrict__ l, int tid) {
  async16(g + tid * 16,         l + tid * 16);
  async16(g + 4096 + tid * 16,  l + 4096 + tid * 16);
  async16(g + 8192 + tid * 16,  l + 8192 + tid * 16);
  if (tid < 32) async16(g + 12288 + tid * 16, l + 12288 + tid * 16);
}

// v_permlane32_swap_b32: a' = {a.lanes0-31, b.lanes0-31}, b' = {a.hi, b.hi}
__device__ __forceinline__ void permswap32(u32& a, u32& b) {
#if __has_builtin(__builtin_amdgcn_permlane32_swap)
  u32x2 r = __builtin_amdgcn_permlane32_swap(a, b, false, false);
  a = r[0]; b = r[1];
#else
  asm("v_permlane32_swap_b32 %0, %1" : "+v"(a), "+v"(b));
#endif
}

// v_permlane16_swap_b32: a' = {a.r0, b.r0, a.r2, b.r2}, b' = {a.r1, b.r1, a.r3, b.r3}
__device__ __forceinline__ void permswap16(u32& a, u32& b) {
#if __has_builtin(__builtin_amdgcn_permlane16_swap)
  u32x2 r = __builtin_amdgcn_permlane16_swap(a, b, false, false);
  a = r[0]; b = r[1];
#else
  asm("v_permlane16_swap_b32 %0, %1" : "+v"(a), "+v"(b));
#endif
}

// ---------------- prologue (r15 layout: 64 blocks x 256 threads) -----------
__global__ __launch_bounds__(256) void rbf_prologue(
    const float* __restrict__ ls, const float* __restrict__ y,
    const float* __restrict__ b, char* __restrict__ rec0,
    float* __restrict__ outz, int zero_out) {
  __shared__ _Float16 sbt[256][17];
  const int tid = threadIdx.x;
  const int j = blockIdx.x * 256 + tid;
  const int tt = j >> 6, jloc = j & 63;
  char* rec = rec0 + (size_t)tt * REC;
  const float nl2g = -ls[0] * 1.4426950408889634f;

  // y row: scaled yn' + plain hi/lo split
  const float4* yp = (const float4*)(y + (size_t)j * D);
  float s = 0.f;
  _Float16 hi[32], lo[32];
  #pragma unroll
  for (int c = 0; c < 8; ++c) {
    float4 v = yp[c];
    float f[4] = {v.x, v.y, v.z, v.w};
    #pragma unroll
    for (int k = 0; k < 4; ++k) {
      s = fmaf(f[k], f[k], s);
      _Float16 h = (_Float16)f[k];
      hi[c*4+k] = h;
      lo[c*4+k] = (_Float16)(f[k] - (float)h);
    }
  }
  ((float*)rec)[jloc] = nl2g * s;
  #pragma unroll
  for (int c = 0; c < 4; ++c) {
    *(half8*)(rec + YH_OFF + jloc * 80 + c * 16) = *(half8*)&hi[c*8];
    *(half8*)(rec + YL_OFF + jloc * 80 + c * 16) = *(half8*)&lo[c*8];
  }

  // b: LDS transpose -> bTh[v][jloc] rows (stride 72 halves)
  const float4* bp = (const float4*)(b + (size_t)j * DV);
  #pragma unroll
  for (int c = 0; c < 4; ++c) {
    float4 v = bp[c];
    sbt[tid][c*4+0] = (_Float16)v.x; sbt[tid][c*4+1] = (_Float16)v.y;
    sbt[tid][c*4+2] = (_Float16)v.z; sbt[tid][c*4+3] = (_Float16)v.w;
  }
  __syncthreads();
  #pragma unroll
  for (int r = 0; r < 2; ++r) {
    int cch = r * 256 + tid;                 // 512 chunks of 16B (4 tiles/block)
    int t4 = cch >> 7, rem = cch & 127, v = rem >> 3, jg = rem & 7;
    _Float16 tmp[8];
    #pragma unroll
    for (int k = 0; k < 8; ++k) tmp[k] = sbt[t4*64 + jg*8 + k][v];
    *(half8*)(rec0 + (size_t)(blockIdx.x*4 + t4)*REC + BT_OFF + v*144 + jg*16) =
        *(half8*)tmp;
  }

  // zero d_out (fused memset, atomic path only)
  if (zero_out) {
    float4 z = {0.f, 0.f, 0.f, 0.f};
    float4* ozp = (float4*)outz;
    #pragma unroll
    for (int r = 0; r < 4; ++r) ozp[blockIdx.x * 1024 + r * 256 + tid] = z;
  }
}

// ---------------- main MFMA kernel (MODE 0: atomic out, 1: partial slabs) --
template <int MODE>
__global__ __launch_bounds__(256, 4) void rbf_mfma(
    const float* __restrict__ ls, const float* __restrict__ x,
    const char* __restrict__ rec0, float* __restrict__ out,
    float* __restrict__ part) {
  __shared__ __align__(16) char SB[2][REC];            // 25600 B

  const int tid  = threadIdx.x;
  const int lane = tid & 63, w = tid >> 6;
  const int t = lane & 15, q = lane >> 4;
  const int iblk = blockIdx.x & 63, jseg = blockIdx.x >> 6;
  const int tseg = jseg * TILES;

  const float nl2g = -ls[0] * 1.4426950408889634f;
  const float m2g  = -2.0f * nl2g;            // positive; xs = m2g * x

  // x fragments (4 per wave): xs = (-2*nl2g)*x split hi/lo; xn' = nl2g*xn+14
  half8 xh[4], xl[4];
  float xns[4];
  #pragma unroll
  for (int f = 0; f < 4; ++f) {
    const int row = iblk * IBLK + f * 64 + w * 16 + t;
    const float4* xp = (const float4*)(x + (size_t)row * D + q * 8);
    float4 a0 = xp[0], a1 = xp[1];
    float fv[8] = {a0.x,a0.y,a0.z,a0.w,a1.x,a1.y,a1.z,a1.w};
    float s = 0.f;
    #pragma unroll
    for (int k = 0; k < 8; ++k) {
      s = fmaf(fv[k], fv[k], s);
      float vv = m2g * fv[k];
      _Float16 h = (_Float16)vv;
      xh[f][k] = h;
      xl[f][k] = (_Float16)(vv - (float)h);
    }
    s += __shfl_xor(s, 16);
    s += __shfl_xor(s, 32);
    xns[f] = fmaf(nl2g, s, 14.0f);
  }

  // dual accumulators: PV chain depth 2 -> 1 (summed in epilogue)
  float4_t acc0[4] = {{0,0,0,0},{0,0,0,0},{0,0,0,0},{0,0,0,0}};
  float4_t acc1[4] = {{0,0,0,0},{0,0,0,0},{0,0,0,0},{0,0,0,0}};

  stage_tile(rec0 + (size_t)tseg * REC, &SB[0][0], tid);
  __syncthreads();

  for (int k = 0; k < TILES; ++k) {
    if (k + 1 < TILES)
      stage_tile(rec0 + (size_t)(tseg + k + 1) * REC, &SB[(k + 1) & 1][0], tid);

    const char* rec = &SB[k & 1][0];
    const float* ynp = (const float*)rec;
    const char* yhp = rec + YH_OFF;
    const char* ylp = rec + YL_OFF;
    const _Float16* btp = (const _Float16*)(rec + BT_OFF);

    // per-tile y fragments, yn' vec, bT rows: read once, reuse over 4 frags
    half8 ah[4], al[4];
    float4_t yn4[4];
    #pragma unroll
    for (int s = 0; s < 4; ++s) {
      ah[s]  = *(const half8*)(yhp + (s * 16 + t) * 80 + q * 16);
      al[s]  = *(const half8*)(ylp + (s * 16 + t) * 80 + q * 16);
      yn4[s] = *(const float4_t*)(ynp + s * 16 + q * 4);
    }
    const half8 bh0 = *(const half8*)(btp + t * PTS + q * 8);
    const half8 bh1 = *(const half8*)(btp + t * PTS + 32 + q * 8);

    #pragma unroll
    for (int f = 0; f < 4; ++f) {
      const float4_t xns4 = {xns[f], xns[f], xns[f], xns[f]};
      // S[s][r]: packed half2 of P[i=t][j=s*16+q*4+{2r,2r+1}] (C-layout)
      u32 S[4][2];
      #pragma unroll
      for (int s = 0; s < 4; ++s) {
        // c/d split: two PARALLEL depth-2 MFMA chains (latency), one add.
        //   c = nl2g*(xn+yn)+14 + ah*xh ; d = ah*xl + al*xh
        float4_t c = yn4[s] + xns4;
        float4_t d = {0.f, 0.f, 0.f, 0.f};
        c = __builtin_amdgcn_mfma_f32_16x16x32_f16(ah[s], xh[f], c, 0, 0, 0);
        d = __builtin_amdgcn_mfma_f32_16x16x32_f16(ah[s], xl[f], d, 0, 0, 0);
        d = __builtin_amdgcn_mfma_f32_16x16x32_f16(al[s], xh[f], d, 0, 0, 0);
        // raw v_exp_f32: exact for args in [-210, 14]
        float p0 = __builtin_amdgcn_exp2f(c[0] + d[0]);
        float p1 = __builtin_amdgcn_exp2f(c[1] + d[1]);
        float p2 = __builtin_amdgcn_exp2f(c[2] + d[2]);
        float p3 = __builtin_amdgcn_exp2f(c[3] + d[3]);
        union { cvt2_t c2; u32 u; } w0, w1;
        w0.c2 = __builtin_amdgcn_cvt_pkrtz(p0, p1);
        w1.c2 = __builtin_amdgcn_cvt_pkrtz(p2, p3);
        S[s][0] = w0.u; S[s][1] = w1.u;
      }
      // In-register C->B transpose (i=lane&15 invariant in both layouts):
      //   permlane32_swap then permlane16_swap on (S[0][r],S[1][r]) yields
      //   exactly (T0[r], T0[2+r]); s=2,3 -> pt1.
      u32 t0[4], t1[4];
      #pragma unroll
      for (int r = 0; r < 2; ++r) {
        u32 a = S[0][r], b = S[1][r];
        permswap32(a, b); permswap16(a, b);
        t0[r] = a; t0[2 + r] = b;
        a = S[2][r]; b = S[3][r];
        permswap32(a, b); permswap16(a, b);
        t1[r] = a; t1[2 + r] = b;
      }
      union { u32 u[4]; half8 h; } up0, up1;
      up0.u[0] = t0[0]; up0.u[1] = t0[1]; up0.u[2] = t0[2]; up0.u[3] = t0[3];
      up1.u[0] = t1[0]; up1.u[1] = t1[1]; up1.u[2] = t1[2]; up1.u[3] = t1[3];
      // independent PV chains (acc0, acc1)
      acc0[f] = __builtin_amdgcn_mfma_f32_16x16x32_f16(bh0, up0.h, acc0[f], 0, 0, 0);
      acc1[f] = __builtin_amdgcn_mfma_f32_16x16x32_f16(bh1, up1.h, acc1[f], 0, 0, 0);
    }
    __syncthreads();   // drains staging vmcnt; protects SB double buffer
  }

  #pragma unroll
  for (int f = 0; f < 4; ++f) {
    const int row = iblk * IBLK + f * 64 + w * 16 + t;
    float4_t a = acc0[f] + acc1[f];
    if (MODE == 0) {
      const float sc = 0.00006103515625f;  // 2^-14
      float* orow = out + (size_t)row * DV + q * 4;
      #pragma unroll
      for (int r = 0; r < 4; ++r) atomicAdd(&orow[r], a[r] * sc);
    } else {
      // raw acc; 2^-14 scale folded into rbf_reduce
      *(float4_t*)(part + ((size_t)jseg * NPTS + row) * DV + q * 4) = a;
    }
  }
}

// ---------------- reduce: out = 2^-14 * sum of 16 partial slabs ------------
__global__ __launch_bounds__(256) void rbf_reduce(
    const float4_t* __restrict__ part, float4_t* __restrict__ out) {
  const int i = blockIdx.x * 256 + threadIdx.x;   // 0..65535 float4s
  float4_t s = part[i];
  #pragma unroll
  for (int k = 1; k < JSPLIT; ++k) s += part[(size_t)k * PART_F4 + i];
  out[i] = s * 0.00006103515625f;                 // 2^-14
}

// ---------------- fallback (round-0 fp32 kernel, no ws) ----------------
#define BJ     128
#define BLOCK  256
#define FJSPLIT 32
#define SYP    36

__global__ __launch_bounds__(BLOCK) void rbf_fp32_kernel(
    const float* __restrict__ ls, const float* __restrict__ x,
    const float* __restrict__ y, const float* __restrict__ b,
    float* __restrict__ out, int N, int M) {
  __shared__ float sy[BJ * SYP];
  __shared__ float sb[BJ * DV];
  __shared__ float syn[BJ];
  const int itiles = N / BLOCK;
  const int itile  = blockIdx.x & (itiles - 1);
  const int jseg   = blockIdx.x / itiles;
  const int i      = itile * BLOCK + threadIdx.x;
  const int jlen   = M / FJSPLIT;
  const int j0     = jseg * jlen;
  const float g    = ls[0];
  const float nl2g = -g * 1.4426950408889634f;
  float xr[D]; float xn = 0.f;
  {
    const float4* xp = (const float4*)(x + (size_t)i * D);
    #pragma unroll
    for (int qq = 0; qq < D / 4; ++qq) {
      float4 v = xp[qq];
      xr[4*qq+0]=v.x; xr[4*qq+1]=v.y; xr[4*qq+2]=v.z; xr[4*qq+3]=v.w;
      xn += v.x*v.x + v.y*v.y + v.z*v.z + v.w*v.w;
    }
  }
  float acc[DV];
  #pragma unroll
  for (int v = 0; v < DV; ++v) acc[v] = 0.f;
  for (int jt = j0; jt < j0 + jlen; jt += BJ) {
    {
      const float4* src = (const float4*)(y + (size_t)jt * D);
      #pragma unroll
      for (int r = 0; r < (BJ * D / 4) / BLOCK; ++r) {
        int e4 = r * BLOCK + threadIdx.x;
        int j  = e4 >> 3; int dq = e4 & 7;
        *(float4*)&sy[j * SYP + dq * 4] = src[e4];
      }
      const float4* bsrc = (const float4*)(b + (size_t)jt * DV);
      #pragma unroll
      for (int r = 0; r < (BJ * DV / 4) / BLOCK; ++r) {
        int e4 = r * BLOCK + threadIdx.x;
        *(float4*)&sb[e4 * 4] = bsrc[e4];
      }
    }
    __syncthreads();
    if (threadIdx.x < BJ) {
      const float* row = &sy[threadIdx.x * SYP];
      float s0=0,s1=0,s2=0,s3=0;
      #pragma unroll
      for (int d = 0; d < D; d += 4) {
        s0=fmaf(row[d+0],row[d+0],s0); s1=fmaf(row[d+1],row[d+1],s1);
        s2=fmaf(row[d+2],row[d+2],s2); s3=fmaf(row[d+3],row[d+3],s3);
      }
      syn[threadIdx.x] = (s0+s1)+(s2+s3);
    }
    __syncthreads();
    #pragma unroll 2
    for (int j = 0; j < BJ; ++j) {
      const float* yrow = &sy[j * SYP];
      float d0=0,d1=0,d2=0,d3=0;
      #pragma unroll
      for (int d = 0; d < D; d += 4) {
        d0=fmaf(xr[d+0],yrow[d+0],d0); d1=fmaf(xr[d+1],yrow[d+1],d1);
        d2=fmaf(xr[d+2],yrow[d+2],d2); d3=fmaf(xr[d+3],yrow[d+3],d3);
      }
      float dot=(d0+d1)+(d2+d3);
      float sq = fmaxf(xn + syn[j] - 2.0f*dot, 0.0f);
      float p  = exp2f(nl2g * sq);
      const float* brow = &sb[j * DV];
      #pragma unroll
      for (int v = 0; v < DV; ++v) acc[v] = fmaf(p, brow[v], acc[v]);
    }
    __syncthreads();
  }
  float* orow = out + (size_t)i * DV;
  #pragma unroll
  for (int v = 0; v < DV; ++v) atomicAdd(&orow[v], acc[v]);
}

extern "C" void kernel_launch(void* const* d_in, const int* in_sizes, int n_in,
                              void* d_out, int out_size, void* d_ws, size_t ws_size,
                              hipStream_t stream) {
  const float* ls = (const float*)d_in[0];
  const float* x  = (const float*)d_in[1];
  const float* y  = (const float*)d_in[2];
  const float* b  = (const float*)d_in[3];
  float* out = (float*)d_out;

  const size_t need_rec  = (size_t)NTILE * REC;                       // 3,276,800 B
  const size_t need_part = need_rec + (size_t)JSPLIT * NPTS * DV * 4; // +16 MiB

  if (ws_size >= need_part) {
    char* rec0 = (char*)d_ws;
    float* part = (float*)(rec0 + need_rec);
    rbf_prologue<<<NPTS / 256, 256, 0, stream>>>(ls, y, b, rec0, out, 0);
    dim3 grid((NPTS / IBLK) * JSPLIT);       // 64 * 16 = 1024
    rbf_mfma<1><<<grid, 256, 0, stream>>>(ls, x, rec0, out, part);
    rbf_reduce<<<PART_F4 / 256, 256, 0, stream>>>((const float4_t*)part,
                                                  (float4_t*)out);
  } else if (ws_size >= need_rec) {
    char* rec0 = (char*)d_ws;
    rbf_prologue<<<NPTS / 256, 256, 0, stream>>>(ls, y, b, rec0, out, 1);
    dim3 grid((NPTS / IBLK) * JSPLIT);
    rbf_mfma<0><<<grid, 256, 0, stream>>>(ls, x, rec0, out, nullptr);
  } else {
    (void)hipMemsetAsync(d_out, 0, (size_t)out_size * sizeof(float), stream);
    dim3 grid((NPTS / BLOCK) * FJSPLIT);
    rbf_fp32_kernel<<<grid, BLOCK, 0, stream>>>(ls, x, y, b, out, NPTS, NPTS);
  }
}

// Round 10
// 135.295 us; speedup vs baseline: 1.3912x; 1.3912x over previous
//
#include <hip/hip_runtime.h>

// out[i,v] = sum_j exp(-g*max(xn_i + yn_j - 2 x_i.y_j, 0)) * b[j,v]
// N=M=16384, D=32, Dv=16, fp32.
//
// Round 18: REVERT r16/r17 body (c/d split + dual acc caused the 263MB
// FETCH explosion -- r17 isolated it; mechanism unclear, result dead).
// Body back to r15 exactly (e-3chain, single acc, no setprio; 82us main,
// 21MB FETCH). Two independent, separable-readout changes:
//  (a) XCD-aware decode swizzle (T1): old mapping put each jseg's 64
//      blocks on all 8 XCDs (every XCD L2 holds all 3.27MB of records).
//      New: xcd=bid&7, rr=bid>>3, jseg=xcd*2+(rr&1), iblk=rr>>1 --
//      bijective; each XCD owns 2 jsegs -> 410KB record working set,
//      each record fetched ~1x per XCD instead of ~8x.
//      Readout: main dur + FETCH_SIZE. Guard: FETCH>50MB => revert.
//  (b) prologue widened to 256 blocks x 64 threads (r16's version, now
//      exonerated: r17 reproduced the FETCH blowup without it).
//      Readout: prologue dispatch dur in the tail.
// Record per 64-j tile: [yn' 256B | yh 64x80B | yl 64x80B | bTh 16x144B] = 12800 B.

#define NPTS 16384
#define D    32
#define DV   16
#define IBLK 256
#define JSPLIT 16
#define JBLK 64
#define NTILE  (NPTS / JBLK)        // 256
#define TILES  (NTILE / JSPLIT)     // 16 per block
#define REC    12800
#define YH_OFF 256
#define YL_OFF 5376
#define BT_OFF 10496
#define PTS    72                   // bT row stride in halves
#define PART_F4 (NPTS * DV / 4)     // 65536 float4s per slab

typedef _Float16 half8   __attribute__((ext_vector_type(8)));
typedef __fp16   cvt2_t  __attribute__((ext_vector_type(2)));
typedef float    float4_t __attribute__((ext_vector_type(4)));
typedef unsigned int u32;
typedef unsigned int u32x2 __attribute__((ext_vector_type(2)));

__device__ __forceinline__ void async16(const void* g, void* l) {
  __builtin_amdgcn_global_load_lds((const __attribute__((address_space(1))) u32*)g,
                                   (__attribute__((address_space(3))) u32*)l, 16, 0, 0);
}

__device__ __forceinline__ void stage_tile(const char* __restrict__ g,
                                           char* __restrict__ l, int tid) {
  async16(g + tid * 16,         l + tid * 16);
  async16(g + 4096 + tid * 16,  l + 4096 + tid * 16);
  async16(g + 8192 + tid * 16,  l + 8192 + tid * 16);
  if (tid < 32) async16(g + 12288 + tid * 16, l + 12288 + tid * 16);
}

// v_permlane32_swap_b32: a' = {a.lanes0-31, b.lanes0-31}, b' = {a.hi, b.hi}
__device__ __forceinline__ void permswap32(u32& a, u32& b) {
#if __has_builtin(__builtin_amdgcn_permlane32_swap)
  u32x2 r = __builtin_amdgcn_permlane32_swap(a, b, false, false);
  a = r[0]; b = r[1];
#else
  asm("v_permlane32_swap_b32 %0, %1" : "+v"(a), "+v"(b));
#endif
}

// v_permlane16_swap_b32: a' = {a.r0, b.r0, a.r2, b.r2}, b' = {a.r1, b.r1, a.r3, b.r3}
__device__ __forceinline__ void permswap16(u32& a, u32& b) {
#if __has_builtin(__builtin_amdgcn_permlane16_swap)
  u32x2 r = __builtin_amdgcn_permlane16_swap(a, b, false, false);
  a = r[0]; b = r[1];
#else
  asm("v_permlane16_swap_b32 %0, %1" : "+v"(a), "+v"(b));
#endif
}

// ---------------- prologue: one 64-j record per 64-thread block ------------
__global__ __launch_bounds__(64) void rbf_prologue(
    const float* __restrict__ ls, const float* __restrict__ y,
    const float* __restrict__ b, char* __restrict__ rec0,
    float* __restrict__ outz, int zero_out) {
  __shared__ _Float16 sbt[64][17];
  const int tid = threadIdx.x;             // 0..63 == jloc
  const int tt  = blockIdx.x;              // record index 0..255
  const int j   = tt * 64 + tid;
  char* rec = rec0 + (size_t)tt * REC;
  const float nl2g = -ls[0] * 1.4426950408889634f;

  // y row: scaled yn' + plain hi/lo split
  const float4* yp = (const float4*)(y + (size_t)j * D);
  float s = 0.f;
  _Float16 hi[32], lo[32];
  #pragma unroll
  for (int c = 0; c < 8; ++c) {
    float4 v = yp[c];
    float f[4] = {v.x, v.y, v.z, v.w};
    #pragma unroll
    for (int k = 0; k < 4; ++k) {
      s = fmaf(f[k], f[k], s);
      _Float16 h = (_Float16)f[k];
      hi[c*4+k] = h;
      lo[c*4+k] = (_Float16)(f[k] - (float)h);
    }
  }
  ((float*)rec)[tid] = nl2g * s;
  #pragma unroll
  for (int c = 0; c < 4; ++c) {
    *(half8*)(rec + YH_OFF + tid * 80 + c * 16) = *(half8*)&hi[c*8];
    *(half8*)(rec + YL_OFF + tid * 80 + c * 16) = *(half8*)&lo[c*8];
  }

  // b: LDS transpose -> bTh[v][jloc] rows (stride 72 halves)
  const float4* bp = (const float4*)(b + (size_t)j * DV);
  #pragma unroll
  for (int c = 0; c < 4; ++c) {
    float4 v = bp[c];
    sbt[tid][c*4+0] = (_Float16)v.x; sbt[tid][c*4+1] = (_Float16)v.y;
    sbt[tid][c*4+2] = (_Float16)v.z; sbt[tid][c*4+3] = (_Float16)v.w;
  }
  __syncthreads();
  #pragma unroll
  for (int r = 0; r < 2; ++r) {
    int cch = r * 64 + tid;                // 128 chunks of 16B
    int v = cch >> 3, jg = cch & 7;
    _Float16 tmp[8];
    #pragma unroll
    for (int k = 0; k < 8; ++k) tmp[k] = sbt[jg*8 + k][v];
    *(half8*)(rec + BT_OFF + v*144 + jg*16) = *(half8*)tmp;
  }

  // zero d_out (fused memset, atomic path only): 1MB over 256 blocks
  if (zero_out) {
    float4 z = {0.f, 0.f, 0.f, 0.f};
    float4* ozp = (float4*)outz;
    #pragma unroll
    for (int r = 0; r < 4; ++r) ozp[blockIdx.x * 256 + r * 64 + tid] = z;
  }
}

// ---------------- main MFMA kernel (MODE 0: atomic out, 1: partial slabs) --
template <int MODE>
__global__ __launch_bounds__(256, 4) void rbf_mfma(
    const float* __restrict__ ls, const float* __restrict__ x,
    const char* __restrict__ rec0, float* __restrict__ out,
    float* __restrict__ part) {
  __shared__ __align__(16) char SB[2][REC];            // 25600 B

  const int tid  = threadIdx.x;
  const int lane = tid & 63, w = tid >> 6;
  const int t = lane & 15, q = lane >> 4;
  // XCD-aware decode (T1): XCD = blockIdx%8 (round-robin dispatch). Give
  // each XCD 2 complete jsegs so its L2 only holds 2*16 records (410 KB).
  // Bijective: bid = (iblk*2 + (jseg&1))*8 + (jseg>>1).
  const int xcd = blockIdx.x & 7, rr = blockIdx.x >> 3;
  const int jseg = xcd * 2 + (rr & 1);
  const int iblk = rr >> 1;
  const int tseg = jseg * TILES;

  const float nl2g = -ls[0] * 1.4426950408889634f;
  const float m2g  = -2.0f * nl2g;            // positive; xs = m2g * x

  // x fragments (4 per wave): xs = (-2*nl2g)*x split hi/lo; xn' = nl2g*xn+14
  half8 xh[4], xl[4];
  float xns[4];
  #pragma unroll
  for (int f = 0; f < 4; ++f) {
    const int row = iblk * IBLK + f * 64 + w * 16 + t;
    const float4* xp = (const float4*)(x + (size_t)row * D + q * 8);
    float4 a0 = xp[0], a1 = xp[1];
    float fv[8] = {a0.x,a0.y,a0.z,a0.w,a1.x,a1.y,a1.z,a1.w};
    float s = 0.f;
    #pragma unroll
    for (int k = 0; k < 8; ++k) {
      s = fmaf(fv[k], fv[k], s);
      float vv = m2g * fv[k];
      _Float16 h = (_Float16)vv;
      xh[f][k] = h;
      xl[f][k] = (_Float16)(vv - (float)h);
    }
    s += __shfl_xor(s, 16);
    s += __shfl_xor(s, 32);
    xns[f] = fmaf(nl2g, s, 14.0f);
  }

  float4_t acc[4] = {{0,0,0,0},{0,0,0,0},{0,0,0,0},{0,0,0,0}};

  stage_tile(rec0 + (size_t)tseg * REC, &SB[0][0], tid);
  __syncthreads();

  for (int k = 0; k < TILES; ++k) {
    if (k + 1 < TILES)
      stage_tile(rec0 + (size_t)(tseg + k + 1) * REC, &SB[(k + 1) & 1][0], tid);

    const char* rec = &SB[k & 1][0];
    const float* ynp = (const float*)rec;
    const char* yhp = rec + YH_OFF;
    const char* ylp = rec + YL_OFF;
    const _Float16* btp = (const _Float16*)(rec + BT_OFF);

    // per-tile y fragments, yn' vec, bT rows: read once, reuse over 4 frags
    half8 ah[4], al[4];
    float4_t yn4[4];
    #pragma unroll
    for (int s = 0; s < 4; ++s) {
      ah[s]  = *(const half8*)(yhp + (s * 16 + t) * 80 + q * 16);
      al[s]  = *(const half8*)(ylp + (s * 16 + t) * 80 + q * 16);
      yn4[s] = *(const float4_t*)(ynp + s * 16 + q * 4);
    }
    const half8 bh0 = *(const half8*)(btp + t * PTS + q * 8);
    const half8 bh1 = *(const half8*)(btp + t * PTS + 32 + q * 8);

    #pragma unroll
    for (int f = 0; f < 4; ++f) {
      const float4_t xns4 = {xns[f], xns[f], xns[f], xns[f]};
      // S[s][r]: packed half2 of P[i=t][j=s*16+q*4+{2r,2r+1}] (C-layout)
      u32 S[4][2];
      #pragma unroll
      for (int s = 0; s < 4; ++s) {
        // single chain: e = nl2g*(xn+yn)+14 + nl2g*(-2 x.y), 3-deep MFMA.
        float4_t e = yn4[s] + xns4;
        e = __builtin_amdgcn_mfma_f32_16x16x32_f16(ah[s], xh[f], e, 0, 0, 0);
        e = __builtin_amdgcn_mfma_f32_16x16x32_f16(ah[s], xl[f], e, 0, 0, 0);
        e = __builtin_amdgcn_mfma_f32_16x16x32_f16(al[s], xh[f], e, 0, 0, 0);
        // raw v_exp_f32: exact for args in [-210, 14]
        float p0 = __builtin_amdgcn_exp2f(e[0]);
        float p1 = __builtin_amdgcn_exp2f(e[1]);
        float p2 = __builtin_amdgcn_exp2f(e[2]);
        float p3 = __builtin_amdgcn_exp2f(e[3]);
        union { cvt2_t c2; u32 u; } w0, w1;
        w0.c2 = __builtin_amdgcn_cvt_pkrtz(p0, p1);
        w1.c2 = __builtin_amdgcn_cvt_pkrtz(p2, p3);
        S[s][0] = w0.u; S[s][1] = w1.u;
      }
      // In-register C->B transpose (i=lane&15 invariant in both layouts):
      //   permlane32_swap then permlane16_swap on (S[0][r],S[1][r]) yields
      //   exactly (T0[r], T0[2+r]); s=2,3 -> pt1.
      u32 t0[4], t1[4];
      #pragma unroll
      for (int r = 0; r < 2; ++r) {
        u32 a = S[0][r], b = S[1][r];
        permswap32(a, b); permswap16(a, b);
        t0[r] = a; t0[2 + r] = b;
        a = S[2][r]; b = S[3][r];
        permswap32(a, b); permswap16(a, b);
        t1[r] = a; t1[2 + r] = b;
      }
      union { u32 u[4]; half8 h; } up0, up1;
      up0.u[0] = t0[0]; up0.u[1] = t0[1]; up0.u[2] = t0[2]; up0.u[3] = t0[3];
      up1.u[0] = t1[0]; up1.u[1] = t1[1]; up1.u[2] = t1[2]; up1.u[3] = t1[3];
      acc[f] = __builtin_amdgcn_mfma_f32_16x16x32_f16(bh0, up0.h, acc[f], 0, 0, 0);
      acc[f] = __builtin_amdgcn_mfma_f32_16x16x32_f16(bh1, up1.h, acc[f], 0, 0, 0);
    }
    __syncthreads();   // drains staging vmcnt; protects SB double buffer
  }

  #pragma unroll
  for (int f = 0; f < 4; ++f) {
    const int row = iblk * IBLK + f * 64 + w * 16 + t;
    if (MODE == 0) {
      const float sc = 0.00006103515625f;  // 2^-14
      float* orow = out + (size_t)row * DV + q * 4;
      #pragma unroll
      for (int r = 0; r < 4; ++r) atomicAdd(&orow[r], acc[f][r] * sc);
    } else {
      // raw acc; 2^-14 scale folded into rbf_reduce
      *(float4_t*)(part + ((size_t)jseg * NPTS + row) * DV + q * 4) = acc[f];
    }
  }
}

// ---------------- reduce: out = 2^-14 * sum of 16 partial slabs ------------
__global__ __launch_bounds__(256) void rbf_reduce(
    const float4_t* __restrict__ part, float4_t* __restrict__ out) {
  const int i = blockIdx.x * 256 + threadIdx.x;   // 0..65535 float4s
  float4_t s = part[i];
  #pragma unroll
  for (int k = 1; k < JSPLIT; ++k) s += part[(size_t)k * PART_F4 + i];
  out[i] = s * 0.00006103515625f;                 // 2^-14
}

// ---------------- fallback (round-0 fp32 kernel, no ws) ----------------
#define BJ     128
#define BLOCK  256
#define FJSPLIT 32
#define SYP    36

__global__ __launch_bounds__(BLOCK) void rbf_fp32_kernel(
    const float* __restrict__ ls, const float* __restrict__ x,
    const float* __restrict__ y, const float* __restrict__ b,
    float* __restrict__ out, int N, int M) {
  __shared__ float sy[BJ * SYP];
  __shared__ float sb[BJ * DV];
  __shared__ float syn[BJ];
  const int itiles = N / BLOCK;
  const int itile  = blockIdx.x & (itiles - 1);
  const int jseg   = blockIdx.x / itiles;
  const int i      = itile * BLOCK + threadIdx.x;
  const int jlen   = M / FJSPLIT;
  const int j0     = jseg * jlen;
  const float g    = ls[0];
  const float nl2g = -g * 1.4426950408889634f;
  float xr[D]; float xn = 0.f;
  {
    const float4* xp = (const float4*)(x + (size_t)i * D);
    #pragma unroll
    for (int qq = 0; qq < D / 4; ++qq) {
      float4 v = xp[qq];
      xr[4*qq+0]=v.x; xr[4*qq+1]=v.y; xr[4*qq+2]=v.z; xr[4*qq+3]=v.w;
      xn += v.x*v.x + v.y*v.y + v.z*v.z + v.w*v.w;
    }
  }
  float acc[DV];
  #pragma unroll
  for (int v = 0; v < DV; ++v) acc[v] = 0.f;
  for (int jt = j0; jt < j0 + jlen; jt += BJ) {
    {
      const float4* src = (const float4*)(y + (size_t)jt * D);
      #pragma unroll
      for (int r = 0; r < (BJ * D / 4) / BLOCK; ++r) {
        int e4 = r * BLOCK + threadIdx.x;
        int j  = e4 >> 3; int dq = e4 & 7;
        *(float4*)&sy[j * SYP + dq * 4] = src[e4];
      }
      const float4* bsrc = (const float4*)(b + (size_t)jt * DV);
      #pragma unroll
      for (int r = 0; r < (BJ * DV / 4) / BLOCK; ++r) {
        int e4 = r * BLOCK + threadIdx.x;
        *(float4*)&sb[e4 * 4] = bsrc[e4];
      }
    }
    __syncthreads();
    if (threadIdx.x < BJ) {
      const float* row = &sy[threadIdx.x * SYP];
      float s0=0,s1=0,s2=0,s3=0;
      #pragma unroll
      for (int d = 0; d < D; d += 4) {
        s0=fmaf(row[d+0],row[d+0],s0); s1=fmaf(row[d+1],row[d+1],s1);
        s2=fmaf(row[d+2],row[d+2],s2); s3=fmaf(row[d+3],row[d+3],s3);
      }
      syn[threadIdx.x] = (s0+s1)+(s2+s3);
    }
    __syncthreads();
    #pragma unroll 2
    for (int j = 0; j < BJ; ++j) {
      const float* yrow = &sy[j * SYP];
      float d0=0,d1=0,d2=0,d3=0;
      #pragma unroll
      for (int d = 0; d < D; d += 4) {
        d0=fmaf(xr[d+0],yrow[d+0],d0); d1=fmaf(xr[d+1],yrow[d+1],d1);
        d2=fmaf(xr[d+2],yrow[d+2],d2); d3=fmaf(xr[d+3],yrow[d+3],d3);
      }
      float dot=(d0+d1)+(d2+d3);
      float sq = fmaxf(xn + syn[j] - 2.0f*dot, 0.0f);
      float p  = exp2f(nl2g * sq);
      const float* brow = &sb[j * DV];
      #pragma unroll
      for (int v = 0; v < DV; ++v) acc[v] = fmaf(p, brow[v], acc[v]);
    }
    __syncthreads();
  }
  float* orow = out + (size_t)i * DV;
  #pragma unroll
  for (int v = 0; v < DV; ++v) atomicAdd(&orow[v], acc[v]);
}

extern "C" void kernel_launch(void* const* d_in, const int* in_sizes, int n_in,
                              void* d_out, int out_size, void* d_ws, size_t ws_size,
                              hipStream_t stream) {
  const float* ls = (const float*)d_in[0];
  const float* x  = (const float*)d_in[1];
  const float* y  = (const float*)d_in[2];
  const float* b  = (const float*)d_in[3];
  float* out = (float*)d_out;

  const size_t need_rec  = (size_t)NTILE * REC;                       // 3,276,800 B
  const size_t need_part = need_rec + (size_t)JSPLIT * NPTS * DV * 4; // +16 MiB

  if (ws_size >= need_part) {
    char* rec0 = (char*)d_ws;
    float* part = (float*)(rec0 + need_rec);
    rbf_prologue<<<NTILE, 64, 0, stream>>>(ls, y, b, rec0, out, 0);
    dim3 grid((NPTS / IBLK) * JSPLIT);       // 64 * 16 = 1024
    rbf_mfma<1><<<grid, 256, 0, stream>>>(ls, x, rec0, out, part);
    rbf_reduce<<<PART_F4 / 256, 256, 0, stream>>>((const float4_t*)part,
                                                  (float4_t*)out);
  } else if (ws_size >= need_rec) {
    char* rec0 = (char*)d_ws;
    rbf_prologue<<<NTILE, 64, 0, stream>>>(ls, y, b, rec0, out, 1);
    dim3 grid((NPTS / IBLK) * JSPLIT);
    rbf_mfma<0><<<grid, 256, 0, stream>>>(ls, x, rec0, out, nullptr);
  } else {
    (void)hipMemsetAsync(d_out, 0, (size_t)out_size * sizeof(float), stream);
    dim3 grid((NPTS / BLOCK) * FJSPLIT);
    rbf_fp32_kernel<<<grid, BLOCK, 0, stream>>>(ls, x, y, b, out, NPTS, NPTS);
  }
}